// Round 6
// baseline (270.853 us; speedup 1.0000x reference)
//
#include <hip/hip_runtime.h>

// ---------------------------------------------------------------------------
// Channel_Transformer_WGCNLayer  (B=16, N=1024, C=512)  -- bf16 MFMA pipeline
// All GEMMs: C[M,Nc] = A[M,K] @ Bt[Nc,K]^T  (K contiguous on both operands)
// GEMM: 8-phase 256x256 template (m201-style): BK=64, 8 waves (2Mx4N),
//   128KiB LDS dbuf, XOR-swizzled LDS (slot ^= row&7, both-sides), counted
//   vmcnt(2) at tile starts only, setprio around MFMA quadrants.
// ---------------------------------------------------------------------------

typedef __bf16 bf16x8 __attribute__((ext_vector_type(8)));
typedef float  f32x4  __attribute__((ext_vector_type(4)));

#define DEV __device__ __forceinline__

DEV float bf2f(unsigned short u) {
  union { unsigned i; float f; } x; x.i = ((unsigned)u) << 16; return x.f;
}
DEV unsigned short f2bf(float f) {           // round-to-nearest-even
  unsigned u = __float_as_uint(f);
  u += 0x7fffu + ((u >> 16) & 1u);
  return (unsigned short)(u >> 16);
}
DEV float sigmoidf_(float x) { return 1.0f / (1.0f + __expf(-x)); }

DEV float wave_sum(float v) {
#pragma unroll
  for (int o = 32; o > 0; o >>= 1) v += __shfl_xor(v, o, 64);
  return v;
}
DEV float wave_max(float v) {
#pragma unroll
  for (int o = 32; o > 0; o >>= 1) v = fmaxf(v, __shfl_xor(v, o, 64));
  return v;
}

// async global->LDS, 16B per lane; lds dest is wave-uniform (HW adds lane*16)
DEV void gload16(const unsigned short* g, unsigned short* l) {
  __builtin_amdgcn_global_load_lds(
      (const __attribute__((address_space(1))) unsigned int*)g,
      (__attribute__((address_space(3))) unsigned int*)l, 16, 0, 0);
}

// raw barrier / counted waits (no implicit vmcnt(0) drain, unlike __syncthreads)
#define BAR()        asm volatile("s_barrier" ::: "memory")
#define WAIT_VM(n)   asm volatile("s_waitcnt vmcnt(" #n ")" ::: "memory")

// ---------------------------- f32 -> bf16 cast -----------------------------
__global__ __launch_bounds__(256) void cast_kernel(const float* __restrict__ in,
                                                   unsigned short* __restrict__ out,
                                                   int n4) {
  int g = blockIdx.x * 256 + threadIdx.x;
  if (g >= n4) return;
  float4 v = *(const float4*)(in + (size_t)g * 4);
  ushort4 o;
  o.x = f2bf(v.x); o.y = f2bf(v.y); o.z = f2bf(v.z); o.w = f2bf(v.w);
  *(ushort4*)(out + (size_t)g * 4) = o;
}

// ------------------- degree: d_is[b,n] = rsqrt(sum_m adj*sig) --------------
__global__ __launch_bounds__(256) void sigrow_kernel(const float* __restrict__ adj,
                                                     const float* __restrict__ edge,
                                                     float* __restrict__ dis) {
  __shared__ float sh[4];
  size_t row = blockIdx.x;                 // b*1024 + n
  int n = (int)(row & 1023);
  const float* ar = adj + row * 1024;
  const float* er = edge + (size_t)n * 1024;
  int c = threadIdx.x * 4;
  float4 a4 = *(const float4*)(ar + c);
  float4 e4 = *(const float4*)(er + c);
  float s = a4.x * sigmoidf_(e4.x) + a4.y * sigmoidf_(e4.y) +
            a4.z * sigmoidf_(e4.z) + a4.w * sigmoidf_(e4.w);
  s = wave_sum(s);
  if ((threadIdx.x & 63) == 0) sh[threadIdx.x >> 6] = s;
  __syncthreads();
  if (threadIdx.x == 0) {
    float t = sh[0] + sh[1] + sh[2] + sh[3];
    dis[row] = t > 0.0f ? rsqrtf(t) : 0.0f;
  }
}

// -------------- W_A_norm[b,n,m] = d[n]*adj*sig(edge)*d[m] -> bf16 ----------
__global__ __launch_bounds__(256) void wa_kernel(const float* __restrict__ adj,
                                                 const float* __restrict__ edge,
                                                 const float* __restrict__ dis,
                                                 unsigned short* __restrict__ wa) {
  size_t g = (size_t)blockIdx.x * 256 + threadIdx.x;   // group of 4 along m
  int m = (int)(g & 255) * 4;
  size_t rest = g >> 8;                                // b*1024 + n
  int n = (int)(rest & 1023);
  int b = (int)(rest >> 10);
  float4 a4 = *(const float4*)(adj + rest * 1024 + m);
  float4 e4 = *(const float4*)(edge + (size_t)n * 1024 + m);
  float dn = dis[rest];
  float4 dm = *(const float4*)(dis + (size_t)b * 1024 + m);
  ushort4 o;
  o.x = f2bf(dn * a4.x * sigmoidf_(e4.x) * dm.x);
  o.y = f2bf(dn * a4.y * sigmoidf_(e4.y) * dm.y);
  o.z = f2bf(dn * a4.z * sigmoidf_(e4.z) * dm.z);
  o.w = f2bf(dn * a4.w * sigmoidf_(e4.w) * dm.w);
  *(ushort4*)(wa + g * 4) = o;
}

// --------------------------- LayerNorm over rows ---------------------------
template <int VPT, bool OUTF32>
__global__ __launch_bounds__(256) void ln_kernel(const unsigned short* __restrict__ in,
                                                 const float* __restrict__ gw,
                                                 const float* __restrict__ gb,
                                                 void* __restrict__ out, int D) {
  __shared__ float sh[8];
  size_t row = blockIdx.x;
  const unsigned short* x = in + row * (size_t)D;
  int base = threadIdx.x * VPT;
  float v[VPT];
  if (VPT == 4) {
    ushort4 u = *(const ushort4*)(x + base);
    v[0] = bf2f(u.x); v[1] = bf2f(u.y); v[2] = bf2f(u.z); v[3] = bf2f(u.w);
  } else {
    ushort2 u = *(const ushort2*)(x + base);
    v[0] = bf2f(u.x); v[1] = bf2f(u.y);
  }
  float s = 0.f, sq = 0.f;
#pragma unroll
  for (int i = 0; i < VPT; i++) { s += v[i]; sq += v[i] * v[i]; }
  s = wave_sum(s); sq = wave_sum(sq);
  if ((threadIdx.x & 63) == 0) { sh[threadIdx.x >> 6] = s; sh[4 + (threadIdx.x >> 6)] = sq; }
  __syncthreads();
  s = sh[0] + sh[1] + sh[2] + sh[3];
  sq = sh[4] + sh[5] + sh[6] + sh[7];
  float mean = s / D;
  float var = sq / D - mean * mean;
  float rs = rsqrtf(fmaxf(var, 0.0f) + 1e-5f);
#pragma unroll
  for (int i = 0; i < VPT; i++) {
    float y = (v[i] - mean) * rs * gw[base + i] + gb[base + i];
    if (OUTF32) ((float*)out)[row * D + base + i] = y;
    else        ((unsigned short*)out)[row * D + base + i] = f2bf(y);
  }
}

// ------------------------- softmax over rows of 512 ------------------------
__global__ __launch_bounds__(256) void softmax_kernel(const float* __restrict__ in,
                                                      unsigned short* __restrict__ out) {
  __shared__ float sh[4];
  size_t row = blockIdx.x;
  const float* x = in + row * 512;
  float2 u = *(const float2*)(x + threadIdx.x * 2);
  float a = u.x * 0.03125f, b = u.y * 0.03125f;   // channel_scale = 1024^-0.5
  float m = wave_max(fmaxf(a, b));
  int wid = threadIdx.x >> 6;
  if ((threadIdx.x & 63) == 0) sh[wid] = m;
  __syncthreads();
  m = fmaxf(fmaxf(sh[0], sh[1]), fmaxf(sh[2], sh[3]));
  __syncthreads();
  float e0 = __expf(a - m), e1 = __expf(b - m);
  float s = wave_sum(e0 + e1);
  if ((threadIdx.x & 63) == 0) sh[wid] = s;
  __syncthreads();
  s = sh[0] + sh[1] + sh[2] + sh[3];
  float inv = 1.0f / s;
  ushort2 o; o.x = f2bf(e0 * inv); o.y = f2bf(e1 * inv);
  *(ushort2*)(out + row * 512 + threadIdx.x * 2) = o;
}

// ================= 8-phase 256x256 bf16 MFMA GEMM (m201-style) =============
// C[M,Nc] = A[M,K] @ Bt[Nc,K]^T.  512 threads = 8 waves (2M x 4N), wave tile
// 128x64 (acc[8][4] f32x4).  BK=64, LDS [2buf][256][64] per operand, 128 KiB.
// LDS swizzle: 16B-slot ^= (row&7) (applied on global SRC for staging and on
// ds_read address -> same involution both sides; linear gload_lds dest).
// Staging: per phase one half-tile (2 gloads/wave) of tile tau+1 (ph1-3) or
// tau+2 (ph4).  Tile-start: WAIT_VM(2)+BAR (only the just-issued ph4 pair may
// remain in flight).  Never vmcnt(0) mid-loop (T4).  setprio around MFMA (T5).
#define MFMA16(d, s0, s1) d = __builtin_amdgcn_mfma_f32_16x16x32_bf16(s0, s1, d, 0, 0, 0)

#define STGA(bi, h, kt) do { \
  gload16(gA + (size_t)((h) * 128) * Ksz + (size_t)(kt) * 64, As + (bi) * 16384 + (h) * 8192 + ldst); \
  gload16(gA + (size_t)((h) * 128 + 64) * Ksz + (size_t)(kt) * 64, As + (bi) * 16384 + (h) * 8192 + 4096 + ldst); \
} while (0)
#define STGB(bi, h, kt) do { \
  gload16(gB + (size_t)((h) * 128) * Ksz + (size_t)(kt) * 64, Bs + (bi) * 16384 + (h) * 8192 + ldst); \
  gload16(gB + (size_t)((h) * 128 + 64) * Ksz + (size_t)(kt) * 64, Bs + (bi) * 16384 + (h) * 8192 + 4096 + ldst); \
} while (0)

#define LDA(bi, mh) do { \
  _Pragma("unroll") for (int mf = 0; mf < 4; mf++) { \
    a[mf][0] = *(const bf16x8*)&As[(bi) * 16384 + arow + ((mh) * 4 + mf) * 1024 + xs0]; \
    a[mf][1] = *(const bf16x8*)&As[(bi) * 16384 + arow + ((mh) * 4 + mf) * 1024 + xs1]; \
  } } while (0)
#define LDB(bi, nh) do { \
  _Pragma("unroll") for (int nf = 0; nf < 2; nf++) { \
    bb[(nh) * 2 + nf][0] = *(const bf16x8*)&Bs[(bi) * 16384 + brow + ((nh) * 2 + nf) * 1024 + xs0]; \
    bb[(nh) * 2 + nf][1] = *(const bf16x8*)&Bs[(bi) * 16384 + brow + ((nh) * 2 + nf) * 1024 + xs1]; \
  } } while (0)

#define MM(mh, nh) do { \
  __builtin_amdgcn_s_setprio(1); \
  _Pragma("unroll") for (int mf = 0; mf < 4; mf++) \
  _Pragma("unroll") for (int nf = 0; nf < 2; nf++) { \
    MFMA16(acc[(mh) * 4 + mf][(nh) * 2 + nf], a[mf][0], bb[(nh) * 2 + nf][0]); \
    MFMA16(acc[(mh) * 4 + mf][(nh) * 2 + nf], a[mf][1], bb[(nh) * 2 + nf][1]); \
  } \
  __builtin_amdgcn_s_setprio(0); } while (0)

// tile tau in buf P; stages: ph1-3 -> halves A1,B0,B1 of tau+1 (buf P^1),
// ph4 -> half A0 of tau+2 (buf P).  All stage targets' last reads are >=1
// closing barrier in the past (A halves last read ph3, B halves ph2).
#define TILE_MAIN(P, kt) do { \
  WAIT_VM(2); BAR(); \
  LDB(P, 0); LDA(P, 0); STGA((P) ^ 1, 1, (kt) + 1); MM(0, 0); BAR(); \
  LDB(P, 1);            STGB((P) ^ 1, 0, (kt) + 1); MM(0, 1); BAR(); \
  LDA(P, 1);            STGB((P) ^ 1, 1, (kt) + 1); MM(1, 1); BAR(); \
                        STGA((P), 0, (kt) + 2);     MM(1, 0); \
} while (0)
#define TILE_TAIL0(P, kt) do { \
  WAIT_VM(2); BAR(); \
  LDB(P, 0); LDA(P, 0); STGA((P) ^ 1, 1, (kt) + 1); MM(0, 0); BAR(); \
  LDB(P, 1);            STGB((P) ^ 1, 0, (kt) + 1); MM(0, 1); BAR(); \
  LDA(P, 1);            STGB((P) ^ 1, 1, (kt) + 1); MM(1, 1); BAR(); \
                        MM(1, 0); \
} while (0)
#define TILE_TAIL1(P) do { \
  WAIT_VM(0); BAR(); \
  LDB(P, 0); LDA(P, 0); MM(0, 0); BAR(); \
  LDB(P, 1);            MM(0, 1); BAR(); \
  LDA(P, 1);            MM(1, 1); BAR(); \
                        MM(1, 0); \
} while (0)

template <int BIAS /*0 none,1 row,2 col*/, bool LEAKY, bool RESID, bool OUTF32, bool SPLIT>
__global__ __launch_bounds__(512, 2) void gemm256(
    const unsigned short* __restrict__ A, size_t sA,
    const unsigned short* __restrict__ Bt, size_t sB,
    const float* __restrict__ bias, const float* __restrict__ bias2,
    const unsigned short* __restrict__ resid,
    void* __restrict__ out, void* __restrict__ out2,
    int M, int NcS, int K, int lgx, int lgy, int xh) {
  __shared__ unsigned short As[2 * 16384];   // [buf][256 rows][64] swizzled
  __shared__ unsigned short Bs[2 * 16384];
  // ---- XCD-chunked bijective swizzle (grid divisible by 8) ----
  const int qc = gridDim.x >> 3;
  const int dd = blockIdx.x;
  const int lb = (dd & 7) * qc + (dd >> 3);
  const int x = lb & ((1 << lgx) - 1);
  const int y = (lb >> lgx) & ((1 << lgy) - 1);
  const int b = lb >> (lgx + lgy);

  const int tid = threadIdx.x;
  const int wid = tid >> 6, lane = tid & 63;
  const int wr = wid >> 2, wc = wid & 3;        // 2 x 4 wave grid
  const int l15 = lane & 15, l4 = lane >> 4;
  const int tM = y * 256, tN = x * 256;
  const size_t Ksz = (size_t)K;

  // staging geometry: round g covers rows g*64; lane l -> row +wid*8+(l>>3),
  // 16B slot (l&7); global src col pre-swizzled by ^(row&7) (involution).
  const int srow = wid * 8 + (lane >> 3);
  const int scol = ((lane & 7) ^ ((lane >> 3) & 7)) * 8;
  const unsigned short* gA = A + sA * b + (size_t)(tM + srow) * Ksz + scol;
  const unsigned short* gB = Bt + sB * b + (size_t)(tN + srow) * Ksz + scol;
  const int ldst = wid * 512;                   // wave-uniform LDS base (shorts)

  // ds_read lane bases: addr = row*64 + ((slot ^ (row&7))*8); row&7 == lane&7
  const int xs0 = ((0 * 4 + l4) ^ (lane & 7)) * 8;   // kk=0
  const int xs1 = ((1 * 4 + l4) ^ (lane & 7)) * 8;   // kk=1
  const int arow = (wr * 128 + l15) * 64;            // + mfabs*1024
  const int brow = (wc * 64 + l15) * 64;             // + nf*1024

  f32x4 acc[8][4] = {};
  bf16x8 a[4][2], bb[4][2];

  const int nt = K >> 6;                        // 8 (K=512) or 16 (K=1024)
  // prologue: tile0 fully + A0 of tile1  (10 gloads/wave in flight)
  STGA(0, 0, 0); STGA(0, 1, 0); STGB(0, 0, 0); STGB(0, 1, 0);
  STGA(1, 0, 1);
  for (int kt = 0; kt < nt - 2; kt += 2) {
    TILE_MAIN(0, kt);
    TILE_MAIN(1, kt + 1);
  }
  TILE_TAIL0(0, nt - 2);
  TILE_TAIL1(1);

  // ------------------------------ epilogue ---------------------------------
  const float* bia = bias;
  void* o = out;
  if (SPLIT && x >= xh) { bia = bias2; o = out2; }
  const size_t ob = (size_t)M * NcS * b;
#pragma unroll
  for (int mf = 0; mf < 8; mf++)
#pragma unroll
    for (int nf = 0; nf < 4; nf++) {
      const int cg = tN + wc * 64 + nf * 16 + l15;
      const int rbase = tM + wr * 128 + mf * 16 + l4 * 4;
#pragma unroll
      for (int r = 0; r < 4; r++) {
        const int rg = rbase + r;
        float v = acc[mf][nf][r];
        if (BIAS == 1) v += bia[rg];
        if (BIAS == 2) v += bia[cg];
        if (LEAKY) v = v > 0.0f ? v : 0.01f * v;
        const size_t idx = ob + (size_t)rg * NcS + cg;
        if (RESID) v += bf2f(resid[idx]);
        if (OUTF32) ((float*)o)[idx] = v;
        else        ((unsigned short*)o)[idx] = f2bf(v);
      }
    }
}

// ---------------------------------------------------------------------------
extern "C" void kernel_launch(void* const* d_in, const int* in_sizes, int n_in,
                              void* d_out, int out_size, void* d_ws, size_t ws_size,
                              hipStream_t stream) {
  const float* node_feats = (const float*)d_in[0];   // [16,1024,512]
  const float* adj        = (const float*)d_in[1];   // [16,1024,1024]
  const float* linear_w   = (const float*)d_in[2];   // [512,512]
  const float* linear_b   = (const float*)d_in[3];   // [512]
  const float* q_w        = (const float*)d_in[4];   // [1024,1024]
  const float* q_b        = (const float*)d_in[5];
  const float* k_w        = (const float*)d_in[6];
  const float* k_b        = (const float*)d_in[7];
  const float* v_w        = (const float*)d_in[8];
  const float* v_b        = (const float*)d_in[9];
  const float* n1w        = (const float*)d_in[10];  // [1024]
  const float* n1b        = (const float*)d_in[11];
  const float* n2w        = (const float*)d_in[12];  // [512]
  const float* n2b        = (const float*)d_in[13];
  const float* edge       = (const float*)d_in[14];  // [1024,1024]
  float* out = (float*)d_out;

  const int B = 16, N = 1024, C = 512;
  const size_t MiB = 1u << 20;
  char* w = (char*)d_ws;
  // lifetime-aliased workspace layout (total ~119.1 MiB)
  unsigned short* nf_bf   = (unsigned short*)(w);             // 16 MiB [dies after G1]
  unsigned short* Xt_bf   = (unsigned short*)(w + 16 * MiB);  // 16 MiB [dies after LN1]
  float*          att_raw = (float*)(w);                      // 16 MiB (reuses nf)
  unsigned short* WA_bf   = (unsigned short*)(w);             // 32 MiB (reuses nf+Xt, after softmax)
  unsigned short* Txln    = (unsigned short*)(w + 32 * MiB);  // 16 MiB
  unsigned short* q_bf    = (unsigned short*)(w + 48 * MiB);  // 16 MiB [dies after Gatt]
  unsigned short* X3_bf   = (unsigned short*)(w + 48 * MiB);  // 16 MiB (reuses q)
  unsigned short* k_bf    = (unsigned short*)(w + 64 * MiB);  // 16 MiB [dies after Gatt]
  unsigned short* att_bf  = (unsigned short*)(w + 64 * MiB);  //  8 MiB (reuses k)
  unsigned short* vt_bf   = (unsigned short*)(w + 80 * MiB);  // 16 MiB
  unsigned short* Tx2_bf  = (unsigned short*)(w + 96 * MiB);  // 16 MiB
  unsigned short* lw_bf   = (unsigned short*)(w + 112 * MiB); // 0.5 MiB
  unsigned short* qw_bf   = (unsigned short*)(w + 113 * MiB); // 2 MiB \ adjacent: one
  unsigned short* kw_bf   = (unsigned short*)(w + 115 * MiB); // 2 MiB / [2048,1024] matrix
  unsigned short* vw_bf   = (unsigned short*)(w + 117 * MiB); // 2 MiB
  float*          dis     = (float*)(w + 119 * MiB);          // 64 KiB

  // casts to bf16
  cast_kernel<<<(B * N * C / 4 + 255) / 256, 256, 0, stream>>>(node_feats, nf_bf, B * N * C / 4);
  cast_kernel<<<(C * C / 4 + 255) / 256, 256, 0, stream>>>(linear_w, lw_bf, C * C / 4);
  cast_kernel<<<(N * N / 4 + 255) / 256, 256, 0, stream>>>(q_w, qw_bf, N * N / 4);
  cast_kernel<<<(N * N / 4 + 255) / 256, 256, 0, stream>>>(k_w, kw_bf, N * N / 4);
  cast_kernel<<<(N * N / 4 + 255) / 256, 256, 0, stream>>>(v_w, vw_bf, N * N / 4);

  // degree normalization factors
  sigrow_kernel<<<B * N, 256, 0, stream>>>(adj, edge, dis);

  // G1: Xt[b,o,n] = leaky(lw @ nf^T + lb[o])   M=C, Nc=N, K=C   grid 4x2x16
  gemm256<1, true, false, false, false><<<128, 512, 0, stream>>>(
      lw_bf, 0, nf_bf, (size_t)N * C, linear_b, nullptr, nullptr,
      Xt_bf, nullptr, C, N, C, 2, 1, 999);

  // LN1 over n (D=1024) -> Txln bf16
  ln_kernel<4, false><<<B * C, 256, 0, stream>>>(Xt_bf, n1w, n1b, Txln, N);

  // fused q|k: [b,x,g] = Txln @ [qw;kw]^T + [qb;kb]   M=C, Nc=2048, K=N
  // grid 8x2x16; x<4 -> q, x>=4 -> k (out2/bias2 pre-shifted by -1024 cols)
  gemm256<2, false, false, false, true><<<256, 512, 0, stream>>>(
      Txln, (size_t)C * N, qw_bf, 0, q_b, k_b - 1024, nullptr,
      q_bf, (void*)(k_bf - 1024), C, N, N, 3, 1, 4);

  // v^T: vt[b,g,x] = leaky(v_w @ Txln^T + v_b[g])   M=N, Nc=C, K=N  grid 2x4x16
  gemm256<1, true, false, false, false><<<128, 512, 0, stream>>>(
      vw_bf, 0, Txln, (size_t)C * N, v_b, nullptr, nullptr,
      vt_bf, nullptr, N, C, N, 1, 2, 999);

  // att_raw[b,x,y] = q @ k^T   M=C, Nc=C, K=N   (f32 out)  grid 2x2x16
  gemm256<0, false, false, true, false><<<64, 512, 0, stream>>>(
      q_bf, (size_t)C * N, k_bf, (size_t)C * N, nullptr, nullptr, nullptr,
      att_raw, nullptr, C, C, N, 1, 1, 999);

  // softmax(att_raw * 1/32) -> att_bf
  softmax_kernel<<<B * C, 256, 0, stream>>>(att_raw, att_bf);

  // W_A normalized bf16 (overwrites bytes [0,32MiB): nf/att_raw/Xt all dead)
  wa_kernel<<<B * N * N / 4 / 256, 256, 0, stream>>>(adj, edge, dis, WA_bf);

  // Tx2[b,x,h] = Txln + att @ v    M=C, Nc=N, K=C   (Bt = vt)  grid 4x2x16
  gemm256<0, false, true, false, false><<<128, 512, 0, stream>>>(
      att_bf, (size_t)C * C, vt_bf, (size_t)N * C, nullptr, nullptr, Txln,
      Tx2_bf, nullptr, C, N, C, 2, 1, 999);

  // X3[b,n,o] = W_A @ X2          M=N, Nc=C, K=N   (Bt = Tx2)  grid 2x4x16
  gemm256<0, false, false, false, false><<<128, 512, 0, stream>>>(
      WA_bf, (size_t)N * N, Tx2_bf, (size_t)C * N, nullptr, nullptr, nullptr,
      X3_bf, nullptr, N, C, N, 1, 2, 999);

  // final LN over o (D=512) -> f32 out
  ln_kernel<2, true><<<B * N, 256, 0, stream>>>(X3_bf, n2w, n2b, out, C);
}

// Round 7
// 260.680 us; speedup vs baseline: 1.0390x; 1.0390x over previous
//
#include <hip/hip_runtime.h>

// ---------------------------------------------------------------------------
// Channel_Transformer_WGCNLayer  (B=16, N=1024, C=512)  -- bf16 MFMA pipeline
// All GEMMs: C[M,Nc] = A[M,K] @ Bt[Nc,K]^T  (K contiguous on both operands)
// GEMM: 8-phase 256x256 (m201): BK=64, 8 waves (2Mx4N), 128KiB LDS dbuf,
//   XOR-swizzled LDS (verified: 0 bank conflicts), DEEP staging (4-6 phase
//   look-ahead) with vmcnt(6) at tile entry, setprio around MFMA quadrants.
//   att GEMM uses split-K=2 (partials summed in softmax) for grid fill.
// ---------------------------------------------------------------------------

typedef __bf16 bf16x8 __attribute__((ext_vector_type(8)));
typedef float  f32x4  __attribute__((ext_vector_type(4)));

#define DEV __device__ __forceinline__

DEV float bf2f(unsigned short u) {
  union { unsigned i; float f; } x; x.i = ((unsigned)u) << 16; return x.f;
}
DEV unsigned short f2bf(float f) {           // round-to-nearest-even
  unsigned u = __float_as_uint(f);
  u += 0x7fffu + ((u >> 16) & 1u);
  return (unsigned short)(u >> 16);
}
DEV float sigmoidf_(float x) { return 1.0f / (1.0f + __expf(-x)); }

DEV float wave_sum(float v) {
#pragma unroll
  for (int o = 32; o > 0; o >>= 1) v += __shfl_xor(v, o, 64);
  return v;
}
DEV float wave_max(float v) {
#pragma unroll
  for (int o = 32; o > 0; o >>= 1) v = fmaxf(v, __shfl_xor(v, o, 64));
  return v;
}

// async global->LDS, 16B per lane; lds dest is wave-uniform (HW adds lane*16)
DEV void gload16(const unsigned short* g, unsigned short* l) {
  __builtin_amdgcn_global_load_lds(
      (const __attribute__((address_space(1))) unsigned int*)g,
      (__attribute__((address_space(3))) unsigned int*)l, 16, 0, 0);
}

// raw barrier / counted waits (no implicit vmcnt(0) drain, unlike __syncthreads)
#define BAR()        asm volatile("s_barrier" ::: "memory")
#define WAIT_VM(n)   asm volatile("s_waitcnt vmcnt(" #n ")" ::: "memory")

// ---------------------------- f32 -> bf16 cast -----------------------------
__global__ __launch_bounds__(256) void cast_kernel(const float* __restrict__ in,
                                                   unsigned short* __restrict__ out,
                                                   int n4) {
  int g = blockIdx.x * 256 + threadIdx.x;
  if (g >= n4) return;
  float4 v = *(const float4*)(in + (size_t)g * 4);
  ushort4 o;
  o.x = f2bf(v.x); o.y = f2bf(v.y); o.z = f2bf(v.z); o.w = f2bf(v.w);
  *(ushort4*)(out + (size_t)g * 4) = o;
}

// ------------------- degree: d_is[b,n] = rsqrt(sum_m adj*sig) --------------
__global__ __launch_bounds__(256) void sigrow_kernel(const float* __restrict__ adj,
                                                     const float* __restrict__ edge,
                                                     float* __restrict__ dis) {
  __shared__ float sh[4];
  size_t row = blockIdx.x;                 // b*1024 + n
  int n = (int)(row & 1023);
  const float* ar = adj + row * 1024;
  const float* er = edge + (size_t)n * 1024;
  int c = threadIdx.x * 4;
  float4 a4 = *(const float4*)(ar + c);
  float4 e4 = *(const float4*)(er + c);
  float s = a4.x * sigmoidf_(e4.x) + a4.y * sigmoidf_(e4.y) +
            a4.z * sigmoidf_(e4.z) + a4.w * sigmoidf_(e4.w);
  s = wave_sum(s);
  if ((threadIdx.x & 63) == 0) sh[threadIdx.x >> 6] = s;
  __syncthreads();
  if (threadIdx.x == 0) {
    float t = sh[0] + sh[1] + sh[2] + sh[3];
    dis[row] = t > 0.0f ? rsqrtf(t) : 0.0f;
  }
}

// -------------- W_A_norm[b,n,m] = d[n]*adj*sig(edge)*d[m] -> bf16 ----------
__global__ __launch_bounds__(256) void wa_kernel(const float* __restrict__ adj,
                                                 const float* __restrict__ edge,
                                                 const float* __restrict__ dis,
                                                 unsigned short* __restrict__ wa) {
  size_t g = (size_t)blockIdx.x * 256 + threadIdx.x;   // group of 4 along m
  int m = (int)(g & 255) * 4;
  size_t rest = g >> 8;                                // b*1024 + n
  int n = (int)(rest & 1023);
  int b = (int)(rest >> 10);
  float4 a4 = *(const float4*)(adj + rest * 1024 + m);
  float4 e4 = *(const float4*)(edge + (size_t)n * 1024 + m);
  float dn = dis[rest];
  float4 dm = *(const float4*)(dis + (size_t)b * 1024 + m);
  ushort4 o;
  o.x = f2bf(dn * a4.x * sigmoidf_(e4.x) * dm.x);
  o.y = f2bf(dn * a4.y * sigmoidf_(e4.y) * dm.y);
  o.z = f2bf(dn * a4.z * sigmoidf_(e4.z) * dm.z);
  o.w = f2bf(dn * a4.w * sigmoidf_(e4.w) * dm.w);
  *(ushort4*)(wa + g * 4) = o;
}

// --------------------------- LayerNorm over rows ---------------------------
template <int VPT, bool OUTF32>
__global__ __launch_bounds__(256) void ln_kernel(const unsigned short* __restrict__ in,
                                                 const float* __restrict__ gw,
                                                 const float* __restrict__ gb,
                                                 void* __restrict__ out, int D) {
  __shared__ float sh[8];
  size_t row = blockIdx.x;
  const unsigned short* x = in + row * (size_t)D;
  int base = threadIdx.x * VPT;
  float v[VPT];
  if (VPT == 4) {
    ushort4 u = *(const ushort4*)(x + base);
    v[0] = bf2f(u.x); v[1] = bf2f(u.y); v[2] = bf2f(u.z); v[3] = bf2f(u.w);
  } else {
    ushort2 u = *(const ushort2*)(x + base);
    v[0] = bf2f(u.x); v[1] = bf2f(u.y);
  }
  float s = 0.f, sq = 0.f;
#pragma unroll
  for (int i = 0; i < VPT; i++) { s += v[i]; sq += v[i] * v[i]; }
  s = wave_sum(s); sq = wave_sum(sq);
  if ((threadIdx.x & 63) == 0) { sh[threadIdx.x >> 6] = s; sh[4 + (threadIdx.x >> 6)] = sq; }
  __syncthreads();
  s = sh[0] + sh[1] + sh[2] + sh[3];
  sq = sh[4] + sh[5] + sh[6] + sh[7];
  float mean = s / D;
  float var = sq / D - mean * mean;
  float rs = rsqrtf(fmaxf(var, 0.0f) + 1e-5f);
#pragma unroll
  for (int i = 0; i < VPT; i++) {
    float y = (v[i] - mean) * rs * gw[base + i] + gb[base + i];
    if (OUTF32) ((float*)out)[row * D + base + i] = y;
    else        ((unsigned short*)out)[row * D + base + i] = f2bf(y);
  }
}

// ------------- softmax over rows of 512 (sums 2 split-K partials) ----------
__global__ __launch_bounds__(256) void softmax_kernel(const float* __restrict__ in,
                                                      const float* __restrict__ in2,
                                                      unsigned short* __restrict__ out) {
  __shared__ float sh[4];
  size_t row = blockIdx.x;
  const float* x = in + row * 512;
  const float* x2 = in2 + row * 512;
  float2 u = *(const float2*)(x + threadIdx.x * 2);
  float2 u2 = *(const float2*)(x2 + threadIdx.x * 2);
  float a = (u.x + u2.x) * 0.03125f, b = (u.y + u2.y) * 0.03125f;  // 1024^-0.5
  float m = wave_max(fmaxf(a, b));
  int wid = threadIdx.x >> 6;
  if ((threadIdx.x & 63) == 0) sh[wid] = m;
  __syncthreads();
  m = fmaxf(fmaxf(sh[0], sh[1]), fmaxf(sh[2], sh[3]));
  __syncthreads();
  float e0 = __expf(a - m), e1 = __expf(b - m);
  float s = wave_sum(e0 + e1);
  if ((threadIdx.x & 63) == 0) sh[wid] = s;
  __syncthreads();
  s = sh[0] + sh[1] + sh[2] + sh[3];
  float inv = 1.0f / s;
  ushort2 o; o.x = f2bf(e0 * inv); o.y = f2bf(e1 * inv);
  *(ushort2*)(out + row * 512 + threadIdx.x * 2) = o;
}

// ================= 8-phase 256x256 bf16 MFMA GEMM (m201-style) =============
// 512 thr = 8 waves (2M x 4N), wave tile 128x64 (acc[8][4]).  BK=64,
// LDS [2buf][256][64]/operand (128 KiB).  Swizzle: 16B-slot ^= row&7, applied
// on global SRC (staging) and ds_read addr (same involution, linear LDS dest).
// DEEP staging per tile tau: A1(tau+1)@ph1, B0(tau+2)@ph3, B1+A0(tau+2)@ph4
//   (WAR-safe: B halves of this buf last read ph2; A halves ph3).
// Tile entry: WAIT_VM(6) (= 3 half-tiles in flight, m201 formula) + raw BAR.
#define MFMA16(d, s0, s1) d = __builtin_amdgcn_mfma_f32_16x16x32_bf16(s0, s1, d, 0, 0, 0)

#define STGA(bi, h, kt) do { \
  gload16(gA + (size_t)((h) * 128) * Kr + (size_t)(kt) * 64, As + (bi) * 16384 + (h) * 8192 + ldst); \
  gload16(gA + (size_t)((h) * 128 + 64) * Kr + (size_t)(kt) * 64, As + (bi) * 16384 + (h) * 8192 + 4096 + ldst); \
} while (0)
#define STGB(bi, h, kt) do { \
  gload16(gB + (size_t)((h) * 128) * Kr + (size_t)(kt) * 64, Bs + (bi) * 16384 + (h) * 8192 + ldst); \
  gload16(gB + (size_t)((h) * 128 + 64) * Kr + (size_t)(kt) * 64, Bs + (bi) * 16384 + (h) * 8192 + 4096 + ldst); \
} while (0)

#define LDA(bi, mh) do { \
  _Pragma("unroll") for (int mf = 0; mf < 4; mf++) { \
    a[mf][0] = *(const bf16x8*)&As[(bi) * 16384 + arow + ((mh) * 4 + mf) * 1024 + xs0]; \
    a[mf][1] = *(const bf16x8*)&As[(bi) * 16384 + arow + ((mh) * 4 + mf) * 1024 + xs1]; \
  } } while (0)
#define LDB(bi, nh) do { \
  _Pragma("unroll") for (int nf = 0; nf < 2; nf++) { \
    bb[(nh) * 2 + nf][0] = *(const bf16x8*)&Bs[(bi) * 16384 + brow + ((nh) * 2 + nf) * 1024 + xs0]; \
    bb[(nh) * 2 + nf][1] = *(const bf16x8*)&Bs[(bi) * 16384 + brow + ((nh) * 2 + nf) * 1024 + xs1]; \
  } } while (0)

#define MM(mh, nh) do { \
  __builtin_amdgcn_s_setprio(1); \
  _Pragma("unroll") for (int mf = 0; mf < 4; mf++) \
  _Pragma("unroll") for (int nf = 0; nf < 2; nf++) { \
    MFMA16(acc[(mh) * 4 + mf][(nh) * 2 + nf], a[mf][0], bb[(nh) * 2 + nf][0]); \
    MFMA16(acc[(mh) * 4 + mf][(nh) * 2 + nf], a[mf][1], bb[(nh) * 2 + nf][1]); \
  } \
  __builtin_amdgcn_s_setprio(0); } while (0)

#define TILE_MAIN(P, kt) do { \
  WAIT_VM(6); BAR(); \
  LDB(P, 0); LDA(P, 0); STGA((P) ^ 1, 1, (kt) + 1);       MM(0, 0); BAR(); \
  LDB(P, 1);                                              MM(0, 1); BAR(); \
  LDA(P, 1);            STGB((P), 0, (kt) + 2);           MM(1, 1); BAR(); \
  STGB((P), 1, (kt) + 2); STGA((P), 0, (kt) + 2);         MM(1, 0); \
} while (0)
#define TILE_TAIL0(P, kt) do { \
  WAIT_VM(6); BAR(); \
  LDB(P, 0); LDA(P, 0); STGA((P) ^ 1, 1, (kt) + 1);       MM(0, 0); BAR(); \
  LDB(P, 1);                                              MM(0, 1); BAR(); \
  LDA(P, 1);                                              MM(1, 1); BAR(); \
                                                          MM(1, 0); \
} while (0)
#define TILE_TAIL1(P) do { \
  WAIT_VM(0); BAR(); \
  LDB(P, 0); LDA(P, 0); MM(0, 0); BAR(); \
  LDB(P, 1);            MM(0, 1); BAR(); \
  LDA(P, 1);            MM(1, 1); BAR(); \
                        MM(1, 0); \
} while (0)

template <int BIAS /*0 none,1 row,2 col*/, bool LEAKY, bool RESID, bool OUTF32,
          bool SPLIT, bool SPLITK>
__global__ __launch_bounds__(512, 2) void gemm256(
    const unsigned short* __restrict__ A, size_t sA,
    const unsigned short* __restrict__ Bt, size_t sB,
    const float* __restrict__ bias, const float* __restrict__ bias2,
    const unsigned short* __restrict__ resid,
    void* __restrict__ out, void* __restrict__ out2,
    int M, int NcS, int K, int Kst, int lgx, int lgy, int xh) {
  __shared__ unsigned short As[2 * 16384];   // [buf][256 rows][64] swizzled
  __shared__ unsigned short Bs[2 * 16384];
  // ---- XCD-chunked bijective swizzle (grid divisible by 8) ----
  const int qc = gridDim.x >> 3;
  const int dd = blockIdx.x;
  const int lb = (dd & 7) * qc + (dd >> 3);
  const int x = lb & ((1 << lgx) - 1);
  const int y = (lb >> lgx) & ((1 << lgy) - 1);
  const int b = (lb >> (lgx + lgy)) & 15;
  const int sk = SPLITK ? (lb >> (lgx + lgy + 4)) : 0;

  const int tid = threadIdx.x;
  const int wid = tid >> 6, lane = tid & 63;
  const int wr = wid >> 2, wc = wid & 3;        // 2 x 4 wave grid
  const int l15 = lane & 15, l4 = lane >> 4;
  const int tM = y * 256, tN = x * 256;
  const size_t Kr = (size_t)Kst;

  // staging geometry: lane l -> row wid*8+(l>>3), 16B slot (l&7);
  // global src col pre-swizzled by ^(row&7) (involution).
  const int srow = wid * 8 + (lane >> 3);
  const int scol = ((lane & 7) ^ ((lane >> 3) & 7)) * 8;
  const int koff = sk * K;                      // split-K column offset
  const unsigned short* gA = A + sA * b + (size_t)(tM + srow) * Kr + scol + koff;
  const unsigned short* gB = Bt + sB * b + (size_t)(tN + srow) * Kr + scol + koff;
  const int ldst = wid * 512;                   // wave-uniform LDS base (shorts)

  // ds_read lane bases: addr = row*64 + ((slot ^ (row&7))*8); row&7 == lane&7
  const int xs0 = ((0 * 4 + l4) ^ (lane & 7)) * 8;   // kk=0
  const int xs1 = ((1 * 4 + l4) ^ (lane & 7)) * 8;   // kk=1
  const int arow = (wr * 128 + l15) * 64;            // + mf*1024
  const int brow = (wc * 64 + l15) * 64;             // + nf*1024

  f32x4 acc[8][4] = {};
  bf16x8 a[4][2], bb[4][2];

  const int nt = K >> 6;                        // 8 (K=512) or 16 (K=1024)
  // prologue: tile0 {A0,B0,B1} then A1(0), then tile1 {B0,B1,A0}
  STGA(0, 0, 0); STGB(0, 0, 0); STGB(0, 1, 0);
  STGA(0, 1, 0);
  STGB(1, 0, 1); STGB(1, 1, 1); STGA(1, 0, 1);
  for (int kt = 0; kt < nt - 2; kt += 2) {
    TILE_MAIN(0, kt);
    TILE_MAIN(1, kt + 1);
  }
  TILE_TAIL0(0, nt - 2);
  TILE_TAIL1(1);

  // ------------------------------ epilogue ---------------------------------
  const float* bia = bias;
  void* o = out;
  if (SPLIT && x >= xh) { bia = bias2; o = out2; }
  if (SPLITK && sk) o = out2;
  const size_t ob = (size_t)M * NcS * b;
#pragma unroll
  for (int mf = 0; mf < 8; mf++)
#pragma unroll
    for (int nf = 0; nf < 4; nf++) {
      const int cg = tN + wc * 64 + nf * 16 + l15;
      const int rbase = tM + wr * 128 + mf * 16 + l4 * 4;
#pragma unroll
      for (int r = 0; r < 4; r++) {
        const int rg = rbase + r;
        float v = acc[mf][nf][r];
        if (BIAS == 1) v += bia[rg];
        if (BIAS == 2) v += bia[cg];
        if (LEAKY) v = v > 0.0f ? v : 0.01f * v;
        const size_t idx = ob + (size_t)rg * NcS + cg;
        if (RESID) v += bf2f(resid[idx]);
        if (OUTF32) ((float*)o)[idx] = v;
        else        ((unsigned short*)o)[idx] = f2bf(v);
      }
    }
}

// ---------------------------------------------------------------------------
extern "C" void kernel_launch(void* const* d_in, const int* in_sizes, int n_in,
                              void* d_out, int out_size, void* d_ws, size_t ws_size,
                              hipStream_t stream) {
  const float* node_feats = (const float*)d_in[0];   // [16,1024,512]
  const float* adj        = (const float*)d_in[1];   // [16,1024,1024]
  const float* linear_w   = (const float*)d_in[2];   // [512,512]
  const float* linear_b   = (const float*)d_in[3];   // [512]
  const float* q_w        = (const float*)d_in[4];   // [1024,1024]
  const float* q_b        = (const float*)d_in[5];
  const float* k_w        = (const float*)d_in[6];
  const float* k_b        = (const float*)d_in[7];
  const float* v_w        = (const float*)d_in[8];
  const float* v_b        = (const float*)d_in[9];
  const float* n1w        = (const float*)d_in[10];  // [1024]
  const float* n1b        = (const float*)d_in[11];
  const float* n2w        = (const float*)d_in[12];  // [512]
  const float* n2b        = (const float*)d_in[13];
  const float* edge       = (const float*)d_in[14];  // [1024,1024]
  float* out = (float*)d_out;

  const int B = 16, N = 1024, C = 512;
  const size_t MiB = 1u << 20;
  char* w = (char*)d_ws;
  // lifetime-aliased workspace layout (total ~119.1 MiB)
  unsigned short* nf_bf   = (unsigned short*)(w);             // 16 MiB [dies after G1]
  unsigned short* Xt_bf   = (unsigned short*)(w + 16 * MiB);  // 16 MiB [dies after LN1]
  float*          att_raw = (float*)(w);                      // 16 MiB (reuses nf)
  float*          att_raw2= (float*)(w + 16 * MiB);           // 16 MiB (reuses Xt)
  unsigned short* WA_bf   = (unsigned short*)(w);             // 32 MiB (after softmax)
  unsigned short* Txln    = (unsigned short*)(w + 32 * MiB);  // 16 MiB
  unsigned short* q_bf    = (unsigned short*)(w + 48 * MiB);  // 16 MiB [dies after att]
  unsigned short* X3_bf   = (unsigned short*)(w + 48 * MiB);  // 16 MiB (reuses q)
  unsigned short* k_bf    = (unsigned short*)(w + 64 * MiB);  // 16 MiB [dies after att]
  unsigned short* att_bf  = (unsigned short*)(w + 64 * MiB);  //  8 MiB (reuses k)
  unsigned short* vt_bf   = (unsigned short*)(w + 80 * MiB);  // 16 MiB
  unsigned short* Tx2_bf  = (unsigned short*)(w + 96 * MiB);  // 16 MiB
  unsigned short* lw_bf   = (unsigned short*)(w + 112 * MiB); // 0.5 MiB
  unsigned short* qw_bf   = (unsigned short*)(w + 113 * MiB); // 2 MiB \ adjacent: one
  unsigned short* kw_bf   = (unsigned short*)(w + 115 * MiB); // 2 MiB / [2048,1024] matrix
  unsigned short* vw_bf   = (unsigned short*)(w + 117 * MiB); // 2 MiB
  float*          dis     = (float*)(w + 119 * MiB);          // 64 KiB

  // casts to bf16
  cast_kernel<<<(B * N * C / 4 + 255) / 256, 256, 0, stream>>>(node_feats, nf_bf, B * N * C / 4);
  cast_kernel<<<(C * C / 4 + 255) / 256, 256, 0, stream>>>(linear_w, lw_bf, C * C / 4);
  cast_kernel<<<(N * N / 4 + 255) / 256, 256, 0, stream>>>(q_w, qw_bf, N * N / 4);
  cast_kernel<<<(N * N / 4 + 255) / 256, 256, 0, stream>>>(k_w, kw_bf, N * N / 4);
  cast_kernel<<<(N * N / 4 + 255) / 256, 256, 0, stream>>>(v_w, vw_bf, N * N / 4);

  // degree normalization factors
  sigrow_kernel<<<B * N, 256, 0, stream>>>(adj, edge, dis);

  // G1: Xt[b,o,n] = leaky(lw @ nf^T + lb[o])   M=C, Nc=N, K=C   grid 4x2x16
  gemm256<1, true, false, false, false, false><<<128, 512, 0, stream>>>(
      lw_bf, 0, nf_bf, (size_t)N * C, linear_b, nullptr, nullptr,
      Xt_bf, nullptr, C, N, C, C, 2, 1, 999);

  // LN1 over n (D=1024) -> Txln bf16
  ln_kernel<4, false><<<B * C, 256, 0, stream>>>(Xt_bf, n1w, n1b, Txln, N);

  // fused q|k: [b,x,g] = Txln @ [qw;kw]^T + [qb;kb]   M=C, Nc=2048, K=N
  // grid 8x2x16; x<4 -> q, x>=4 -> k (out2/bias2 pre-shifted by -1024 cols)
  gemm256<2, false, false, false, true, false><<<256, 512, 0, stream>>>(
      Txln, (size_t)C * N, qw_bf, 0, q_b, k_b - 1024, nullptr,
      q_bf, (void*)(k_bf - 1024), C, N, N, N, 3, 1, 4);

  // v^T: vt[b,g,x] = leaky(v_w @ Txln^T + v_b[g])   M=N, Nc=C, K=N  grid 2x4x16
  gemm256<1, true, false, false, false, false><<<128, 512, 0, stream>>>(
      vw_bf, 0, Txln, (size_t)C * N, v_b, nullptr, nullptr,
      vt_bf, nullptr, N, C, N, N, 1, 2, 999);

  // att partials: att[b,x,y] = q @ k^T   M=C, Nc=C, K=1024 split 2x512
  // grid 2x2x16x2(sk); f32 partials summed in softmax
  gemm256<0, false, false, true, false, true><<<128, 512, 0, stream>>>(
      q_bf, (size_t)C * N, k_bf, (size_t)C * N, nullptr, nullptr, nullptr,
      att_raw, att_raw2, C, C, 512, N, 1, 1, 999);

  // softmax((p0+p1) * 1/32) -> att_bf
  softmax_kernel<<<B * C, 256, 0, stream>>>(att_raw, att_raw2, att_bf);

  // W_A normalized bf16 (overwrites bytes [0,32MiB): partials dead)
  wa_kernel<<<B * N * N / 4 / 256, 256, 0, stream>>>(adj, edge, dis, WA_bf);

  // Tx2[b,x,h] = Txln + att @ v    M=C, Nc=N, K=C   (Bt = vt)  grid 4x2x16
  gemm256<0, false, true, false, false, false><<<128, 512, 0, stream>>>(
      att_bf, (size_t)C * C, vt_bf, (size_t)N * C, nullptr, nullptr, Txln,
      Tx2_bf, nullptr, C, N, C, C, 2, 1, 999);

  // X3[b,n,o] = W_A @ X2          M=N, Nc=C, K=N   (Bt = Tx2)  grid 2x4x16
  gemm256<0, false, false, false, false, false><<<128, 512, 0, stream>>>(
      WA_bf, (size_t)N * N, Tx2_bf, (size_t)C * N, nullptr, nullptr, nullptr,
      X3_bf, nullptr, N, C, N, N, 1, 2, 999);

  // final LN over o (D=512) -> f32 out
  ln_kernel<2, true><<<B * N, 256, 0, stream>>>(X3_bf, n2w, n2b, out, C);
}

// Round 9
// 217.365 us; speedup vs baseline: 1.2461x; 1.1993x over previous
//
#include <hip/hip_runtime.h>

// ---------------------------------------------------------------------------
// Channel_Transformer_WGCNLayer  (B=16, N=1024, C=512)  -- bf16 MFMA pipeline
// All GEMMs: C[M,Nc] = A[M,K] @ Bt[Nc,K]^T  (K contiguous on both operands)
// GEMM: m201 8-phase 256xBNT (BNT=256|128): BK=64, 8 waves, LDS dbuf,
//   XOR-swizzle (0 conflicts, verified), phase shape {reads; BAR; SB0;
//   setprio+MFMA; SB0; BAR}, entry vmcnt(8|6) only.
//   Stage placement derived from LAST-READ analysis (round-8 race fix):
//     A rows are split by wr (LDA(P,1) reads rows wr*128+64..127 -> touches
//     half A0!), B rows by wc (LDB spans both halves).  So:
//     ph3 (after B's last read ph2): ALL B stages.  ph4 (after A's last read
//     ph3): ALL A stages.  No interval holds a read+write of the same array.
// ---------------------------------------------------------------------------

typedef __bf16 bf16x8 __attribute__((ext_vector_type(8)));
typedef float  f32x4  __attribute__((ext_vector_type(4)));

#define DEV __device__ __forceinline__

DEV float bf2f(unsigned short u) {
  union { unsigned i; float f; } x; x.i = ((unsigned)u) << 16; return x.f;
}
DEV unsigned short f2bf(float f) {           // round-to-nearest-even
  unsigned u = __float_as_uint(f);
  u += 0x7fffu + ((u >> 16) & 1u);
  return (unsigned short)(u >> 16);
}
DEV float sigmoidf_(float x) { return 1.0f / (1.0f + __expf(-x)); }

DEV float wave_sum(float v) {
#pragma unroll
  for (int o = 32; o > 0; o >>= 1) v += __shfl_xor(v, o, 64);
  return v;
}
DEV float wave_max(float v) {
#pragma unroll
  for (int o = 32; o > 0; o >>= 1) v = fmaxf(v, __shfl_xor(v, o, 64));
  return v;
}

// async global->LDS, 16B per lane; lds dest is wave-uniform (HW adds lane*16)
DEV void gload16(const unsigned short* g, unsigned short* l) {
  __builtin_amdgcn_global_load_lds(
      (const __attribute__((address_space(1))) unsigned int*)g,
      (__attribute__((address_space(3))) unsigned int*)l, 16, 0, 0);
}

// raw barrier / counted waits (no implicit vmcnt(0) drain, unlike __syncthreads)
#define BAR()        asm volatile("s_barrier" ::: "memory")
#define WAIT_VM(n)   asm volatile("s_waitcnt vmcnt(" #n ")" ::: "memory")
#define SB0()        __builtin_amdgcn_sched_barrier(0)

// ---------------------------- f32 -> bf16 cast -----------------------------
__global__ __launch_bounds__(256) void cast_kernel(const float* __restrict__ in,
                                                   unsigned short* __restrict__ out,
                                                   int n4) {
  int g = blockIdx.x * 256 + threadIdx.x;
  if (g >= n4) return;
  float4 v = *(const float4*)(in + (size_t)g * 4);
  ushort4 o;
  o.x = f2bf(v.x); o.y = f2bf(v.y); o.z = f2bf(v.z); o.w = f2bf(v.w);
  *(ushort4*)(out + (size_t)g * 4) = o;
}

// ------------------- degree: d_is[b,n] = rsqrt(sum_m adj*sig) --------------
__global__ __launch_bounds__(256) void sigrow_kernel(const float* __restrict__ adj,
                                                     const float* __restrict__ edge,
                                                     float* __restrict__ dis) {
  __shared__ float sh[4];
  size_t row = blockIdx.x;                 // b*1024 + n
  int n = (int)(row & 1023);
  const float* ar = adj + row * 1024;
  const float* er = edge + (size_t)n * 1024;
  int c = threadIdx.x * 4;
  float4 a4 = *(const float4*)(ar + c);
  float4 e4 = *(const float4*)(er + c);
  float s = a4.x * sigmoidf_(e4.x) + a4.y * sigmoidf_(e4.y) +
            a4.z * sigmoidf_(e4.z) + a4.w * sigmoidf_(e4.w);
  s = wave_sum(s);
  if ((threadIdx.x & 63) == 0) sh[threadIdx.x >> 6] = s;
  __syncthreads();
  if (threadIdx.x == 0) {
    float t = sh[0] + sh[1] + sh[2] + sh[3];
    dis[row] = t > 0.0f ? rsqrtf(t) : 0.0f;
  }
}

// -------------- W_A_norm[b,n,m] = d[n]*adj*sig(edge)*d[m] -> bf16 ----------
__global__ __launch_bounds__(256) void wa_kernel(const float* __restrict__ adj,
                                                 const float* __restrict__ edge,
                                                 const float* __restrict__ dis,
                                                 unsigned short* __restrict__ wa) {
  size_t g = (size_t)blockIdx.x * 256 + threadIdx.x;   // group of 4 along m
  int m = (int)(g & 255) * 4;
  size_t rest = g >> 8;                                // b*1024 + n
  int n = (int)(rest & 1023);
  int b = (int)(rest >> 10);
  float4 a4 = *(const float4*)(adj + rest * 1024 + m);
  float4 e4 = *(const float4*)(edge + (size_t)n * 1024 + m);
  float dn = dis[rest];
  float4 dm = *(const float4*)(dis + (size_t)b * 1024 + m);
  ushort4 o;
  o.x = f2bf(dn * a4.x * sigmoidf_(e4.x) * dm.x);
  o.y = f2bf(dn * a4.y * sigmoidf_(e4.y) * dm.y);
  o.z = f2bf(dn * a4.z * sigmoidf_(e4.z) * dm.z);
  o.w = f2bf(dn * a4.w * sigmoidf_(e4.w) * dm.w);
  *(ushort4*)(wa + g * 4) = o;
}

// --------------------------- LayerNorm over rows ---------------------------
template <int VPT, bool OUTF32>
__global__ __launch_bounds__(256) void ln_kernel(const unsigned short* __restrict__ in,
                                                 const float* __restrict__ gw,
                                                 const float* __restrict__ gb,
                                                 void* __restrict__ out, int D) {
  __shared__ float sh[8];
  size_t row = blockIdx.x;
  const unsigned short* x = in + row * (size_t)D;
  int base = threadIdx.x * VPT;
  float v[VPT];
  if (VPT == 4) {
    ushort4 u = *(const ushort4*)(x + base);
    v[0] = bf2f(u.x); v[1] = bf2f(u.y); v[2] = bf2f(u.z); v[3] = bf2f(u.w);
  } else {
    ushort2 u = *(const ushort2*)(x + base);
    v[0] = bf2f(u.x); v[1] = bf2f(u.y);
  }
  float s = 0.f, sq = 0.f;
#pragma unroll
  for (int i = 0; i < VPT; i++) { s += v[i]; sq += v[i] * v[i]; }
  s = wave_sum(s); sq = wave_sum(sq);
  if ((threadIdx.x & 63) == 0) { sh[threadIdx.x >> 6] = s; sh[4 + (threadIdx.x >> 6)] = sq; }
  __syncthreads();
  s = sh[0] + sh[1] + sh[2] + sh[3];
  sq = sh[4] + sh[5] + sh[6] + sh[7];
  float mean = s / D;
  float var = sq / D - mean * mean;
  float rs = rsqrtf(fmaxf(var, 0.0f) + 1e-5f);
#pragma unroll
  for (int i = 0; i < VPT; i++) {
    float y = (v[i] - mean) * rs * gw[base + i] + gb[base + i];
    if (OUTF32) ((float*)out)[row * D + base + i] = y;
    else        ((unsigned short*)out)[row * D + base + i] = f2bf(y);
  }
}

// ------------- softmax over rows of 512 (sums 2 split-K partials) ----------
__global__ __launch_bounds__(256) void softmax_kernel(const float* __restrict__ in,
                                                      const float* __restrict__ in2,
                                                      unsigned short* __restrict__ out) {
  __shared__ float sh[4];
  size_t row = blockIdx.x;
  const float* x = in + row * 512;
  const float* x2 = in2 + row * 512;
  float2 u = *(const float2*)(x + threadIdx.x * 2);
  float2 u2 = *(const float2*)(x2 + threadIdx.x * 2);
  float a = (u.x + u2.x) * 0.03125f, b = (u.y + u2.y) * 0.03125f;  // 1024^-0.5
  float m = wave_max(fmaxf(a, b));
  int wid = threadIdx.x >> 6;
  if ((threadIdx.x & 63) == 0) sh[wid] = m;
  __syncthreads();
  m = fmaxf(fmaxf(sh[0], sh[1]), fmaxf(sh[2], sh[3]));
  __syncthreads();
  float e0 = __expf(a - m), e1 = __expf(b - m);
  float s = wave_sum(e0 + e1);
  if ((threadIdx.x & 63) == 0) sh[wid] = s;
  __syncthreads();
  s = sh[0] + sh[1] + sh[2] + sh[3];
  float inv = 1.0f / s;
  ushort2 o; o.x = f2bf(e0 * inv); o.y = f2bf(e1 * inv);
  *(ushort2*)(out + row * 512 + threadIdx.x * 2) = o;
}

// ============== m201 8-phase 256xBNT bf16 MFMA GEMM (BNT=256|128) ==========
// 512 thr = 8 waves (2M x 4N).  BNT=256: wave tile 128x64, acc[8][4], 8
// loads/K-tile, entry vmcnt(8).  BNT=128: wave tile 128x32, acc[8][2], 6
// loads/K-tile, entry vmcnt(6).
// LAST-READ map (buf P, tile t):  A half0 rows 0-127: read ph1 (wr=0 LDA0)
// AND ph3 (wr=0 LDA1).  A half1 rows 128-255: ph1/ph3 (wr=1).  B halves:
// read ph1 (LDB0) and ph2 (LDB1) across wc.  => stages: B @ph3, A @ph4.
#define MFMA16(d, s0, s1) d = __builtin_amdgcn_mfma_f32_16x16x32_bf16(s0, s1, d, 0, 0, 0)

#define STGA(bi, h, kt) do { \
  gload16(gA + (size_t)((h) * 128) * Kr + (size_t)(kt) * 64, As + (bi) * 16384 + (h) * 8192 + ldst); \
  gload16(gA + (size_t)((h) * 128 + 64) * Kr + (size_t)(kt) * 64, As + (bi) * 16384 + (h) * 8192 + 4096 + ldst); \
} while (0)
#define STGB(bi, h, kt) do { \
  gload16(gB + (size_t)((h) * 128) * Kr + (size_t)(kt) * 64, Bs + (bi) * BSZ + (h) * 8192 + ldst); \
  gload16(gB + (size_t)((h) * 128 + 64) * Kr + (size_t)(kt) * 64, Bs + (bi) * BSZ + (h) * 8192 + 4096 + ldst); \
} while (0)

#define LDA(bi, mh) do { \
  _Pragma("unroll") for (int mf = 0; mf < 4; mf++) { \
    a[mf][0] = *(const bf16x8*)&As[(bi) * 16384 + arow + ((mh) * 4 + mf) * 1024 + xs0]; \
    a[mf][1] = *(const bf16x8*)&As[(bi) * 16384 + arow + ((mh) * 4 + mf) * 1024 + xs1]; \
  } } while (0)
#define LDB(bi, nh) do { \
  if constexpr (BNT == 256) { \
    _Pragma("unroll") for (int nf = 0; nf < 2; nf++) { \
      bb[(nh) * 2 + nf][0] = *(const bf16x8*)&Bs[(bi) * BSZ + brow + ((nh) * 2 + nf) * 1024 + xs0]; \
      bb[(nh) * 2 + nf][1] = *(const bf16x8*)&Bs[(bi) * BSZ + brow + ((nh) * 2 + nf) * 1024 + xs1]; \
    } \
  } else { \
    _Pragma("unroll") for (int nf = 0; nf < 2; nf++) { \
      bb[nf][0] = *(const bf16x8*)&Bs[(bi) * BSZ + brow + nf * 1024 + xs0]; \
      bb[nf][1] = *(const bf16x8*)&Bs[(bi) * BSZ + brow + nf * 1024 + xs1]; \
    } \
  } } while (0)

#define MMQ(mh, nh) do { \
  __builtin_amdgcn_s_setprio(1); \
  if constexpr (BNT == 256) { \
    _Pragma("unroll") for (int mf = 0; mf < 4; mf++) \
    _Pragma("unroll") for (int nf = 0; nf < 2; nf++) { \
      MFMA16(acc[(mh) * 4 + mf][(nh) * 2 + nf], a[mf][0], bb[(nh) * 2 + nf][0]); \
      MFMA16(acc[(mh) * 4 + mf][(nh) * 2 + nf], a[mf][1], bb[(nh) * 2 + nf][1]); \
    } \
  } else { \
    _Pragma("unroll") for (int mf = 0; mf < 4; mf++) { \
      MFMA16(acc[(mh) * 4 + mf][(nh)], a[mf][0], bb[(nh)][0]); \
      MFMA16(acc[(mh) * 4 + mf][(nh)], a[mf][1], bb[(nh)][1]); \
    } \
  } \
  __builtin_amdgcn_s_setprio(0); } while (0)

// Phase shape per quadrant: {reads/stages interval; BAR; SB0; MFMA; SB0; BAR}.
// SB0 on BOTH sides pins the MFMA cluster inside its interval (the WAR proof
// needs "wave passed the barrier => its ds_reads drained before the MFMA").
#define TILE(P, kt, STG, EW) do { \
  EW; BAR(); \
  LDA(P, 0); LDB(P, 0); \
  BAR(); SB0(); MMQ(0, 0); SB0(); BAR(); \
  if constexpr (BNT == 256) { LDB(P, 1); } \
  BAR(); SB0(); MMQ(0, 1); SB0(); BAR(); \
  LDA(P, 1); \
  if (STG) { STGB(P, 0, (kt) + 2); if constexpr (BNT == 256) { STGB(P, 1, (kt) + 2); } } \
  BAR(); SB0(); MMQ(1, 1); SB0(); BAR(); \
  if (STG) { STGA(P, 0, (kt) + 2); STGA(P, 1, (kt) + 2); } \
  BAR(); SB0(); MMQ(1, 0); SB0(); \
} while (0)

template <int BNT, int BIAS /*0 none,1 row,2 col*/, bool LEAKY, bool RESID,
          bool OUTF32, bool SPLIT, bool SPLITK>
__global__ __launch_bounds__(512, 2) void gemm256(
    const unsigned short* __restrict__ A, size_t sA,
    const unsigned short* __restrict__ Bt, size_t sB,
    const float* __restrict__ bias, const float* __restrict__ bias2,
    const unsigned short* __restrict__ resid,
    void* __restrict__ out, void* __restrict__ out2,
    int M, int NcS, int K, int Kst, int lgx, int lgy, int xh) {
  constexpr int NFR = (BNT == 256) ? 4 : 2;
  constexpr int BSZ = BNT * 64;              // shorts per B buffer
  __shared__ unsigned short As[2 * 16384];   // [buf][256 rows][64] swizzled
  __shared__ unsigned short Bs[2 * BSZ];     // [buf][BNT rows][64] swizzled
  // ---- XCD-chunked bijective swizzle (grid divisible by 8) ----
  const int qc = gridDim.x >> 3;
  const int dd = blockIdx.x;
  const int lb = (dd & 7) * qc + (dd >> 3);
  const int x = lb & ((1 << lgx) - 1);
  const int y = (lb >> lgx) & ((1 << lgy) - 1);
  const int b = (lb >> (lgx + lgy)) & 15;
  const int sk = SPLITK ? (lb >> (lgx + lgy + 4)) : 0;

  const int tid = threadIdx.x;
  const int wid = tid >> 6, lane = tid & 63;
  const int wr = wid >> 2, wc = wid & 3;        // 2 x 4 wave grid
  const int l15 = lane & 15, l4 = lane >> 4;
  const int tM = y * 256, tN = x * BNT;
  const size_t Kr = (size_t)Kst;

  // staging geometry: lane l -> row wid*8+(l>>3), 16B slot (l&7);
  // global src col pre-swizzled by ^(row&7) (involution).
  const int srow = wid * 8 + (lane >> 3);
  const int scol = ((lane & 7) ^ ((lane >> 3) & 7)) * 8;
  const int koff = sk * K;                      // split-K column offset
  const unsigned short* gA = A + sA * b + (size_t)(tM + srow) * Kr + scol + koff;
  const unsigned short* gB = Bt + sB * b + (size_t)(tN + srow) * Kr + scol + koff;
  const int ldst = wid * 512;                   // wave-uniform LDS base (shorts)

  // ds_read lane bases: addr = row*64 + ((slot ^ (row&7))*8); row&7 == lane&7
  const int xs0 = ((0 * 4 + l4) ^ (lane & 7)) * 8;   // kk=0
  const int xs1 = ((1 * 4 + l4) ^ (lane & 7)) * 8;   // kk=1
  const int arow = (wr * 128 + l15) * 64;            // + mf*1024
  const int brow = (wc * (BNT / 4) + l15) * 64;      // + nf*1024

  f32x4 acc[8][NFR] = {};
  bf16x8 a[4][2], bb[NFR][2];

  const int nt = K >> 6;                        // 8 (K=512) or 16 (K=1024)
  // prologue: tiles 0 and 1 fully staged, grouped per tile (oldest-first),
  // intra-tile order B then A (matches the in-loop issue order ph3/ph4).
  STGB(0, 0, 0);
  if constexpr (BNT == 256) { STGB(0, 1, 0); }
  STGA(0, 0, 0); STGA(0, 1, 0);
  STGB(1, 0, 1);
  if constexpr (BNT == 256) { STGB(1, 1, 1); }
  STGA(1, 0, 1); STGA(1, 1, 1);

  if constexpr (BNT == 256) {
    for (int kt = 0; kt < nt - 2; kt += 2) {
      TILE(0, kt, true, WAIT_VM(8));
      TILE(1, kt + 1, true, WAIT_VM(8));
    }
    TILE(0, nt - 2, false, WAIT_VM(8));
    TILE(1, nt - 1, false, WAIT_VM(0));
  } else {
    for (int kt = 0; kt < nt - 2; kt += 2) {
      TILE(0, kt, true, WAIT_VM(6));
      TILE(1, kt + 1, true, WAIT_VM(6));
    }
    TILE(0, nt - 2, false, WAIT_VM(6));
    TILE(1, nt - 1, false, WAIT_VM(0));
  }

  // ------------------------------ epilogue ---------------------------------
  const float* bia = bias;
  void* o = out;
  if (SPLIT && x >= xh) { bia = bias2; o = out2; }
  if (SPLITK && sk) o = out2;
  const size_t ob = (size_t)M * NcS * b;
#pragma unroll
  for (int mf = 0; mf < 8; mf++)
#pragma unroll
    for (int nf = 0; nf < NFR; nf++) {
      const int cg = tN + wc * (BNT / 4) + nf * 16 + l15;
      const int rbase = tM + wr * 128 + mf * 16 + l4 * 4;
#pragma unroll
      for (int r = 0; r < 4; r++) {
        const int rg = rbase + r;
        float v = acc[mf][nf][r];
        if (BIAS == 1) v += bia[rg];
        if (BIAS == 2) v += bia[cg];
        if (LEAKY) v = v > 0.0f ? v : 0.01f * v;
        const size_t idx = ob + (size_t)rg * NcS + cg;
        if (RESID) v += bf2f(resid[idx]);
        if (OUTF32) ((float*)o)[idx] = v;
        else        ((unsigned short*)o)[idx] = f2bf(v);
      }
    }
}

// ---------------------------------------------------------------------------
extern "C" void kernel_launch(void* const* d_in, const int* in_sizes, int n_in,
                              void* d_out, int out_size, void* d_ws, size_t ws_size,
                              hipStream_t stream) {
  const float* node_feats = (const float*)d_in[0];   // [16,1024,512]
  const float* adj        = (const float*)d_in[1];   // [16,1024,1024]
  const float* linear_w   = (const float*)d_in[2];   // [512,512]
  const float* linear_b   = (const float*)d_in[3];   // [512]
  const float* q_w        = (const float*)d_in[4];   // [1024,1024]
  const float* q_b        = (const float*)d_in[5];
  const float* k_w        = (const float*)d_in[6];
  const float* k_b        = (const float*)d_in[7];
  const float* v_w        = (const float*)d_in[8];
  const float* v_b        = (const float*)d_in[9];
  const float* n1w        = (const float*)d_in[10];  // [1024]
  const float* n1b        = (const float*)d_in[11];
  const float* n2w        = (const float*)d_in[12];  // [512]
  const float* n2b        = (const float*)d_in[13];
  const float* edge       = (const float*)d_in[14];  // [1024,1024]
  float* out = (float*)d_out;

  const int B = 16, N = 1024, C = 512;
  const size_t MiB = 1u << 20;
  char* w = (char*)d_ws;
  // lifetime-aliased workspace layout (total ~119.1 MiB)
  unsigned short* nf_bf   = (unsigned short*)(w);             // 16 MiB [dies after G1]
  unsigned short* Xt_bf   = (unsigned short*)(w + 16 * MiB);  // 16 MiB [dies after LN1]
  float*          att_raw = (float*)(w);                      // 16 MiB (reuses nf)
  float*          att_raw2= (float*)(w + 16 * MiB);           // 16 MiB (reuses Xt)
  unsigned short* WA_bf   = (unsigned short*)(w);             // 32 MiB (after softmax)
  unsigned short* Txln    = (unsigned short*)(w + 32 * MiB);  // 16 MiB
  unsigned short* q_bf    = (unsigned short*)(w + 48 * MiB);  // 16 MiB [dies after att]
  unsigned short* X3_bf   = (unsigned short*)(w + 48 * MiB);  // 16 MiB (reuses q)
  unsigned short* k_bf    = (unsigned short*)(w + 64 * MiB);  // 16 MiB [dies after att]
  unsigned short* att_bf  = (unsigned short*)(w + 64 * MiB);  //  8 MiB (reuses k)
  unsigned short* vt_bf   = (unsigned short*)(w + 80 * MiB);  // 16 MiB
  unsigned short* Tx2_bf  = (unsigned short*)(w + 96 * MiB);  // 16 MiB
  unsigned short* lw_bf   = (unsigned short*)(w + 112 * MiB); // 0.5 MiB
  unsigned short* qw_bf   = (unsigned short*)(w + 113 * MiB); // 2 MiB \ adjacent: one
  unsigned short* kw_bf   = (unsigned short*)(w + 115 * MiB); // 2 MiB / [2048,1024] matrix
  unsigned short* vw_bf   = (unsigned short*)(w + 117 * MiB); // 2 MiB
  float*          dis     = (float*)(w + 119 * MiB);          // 64 KiB

  // casts to bf16
  cast_kernel<<<(B * N * C / 4 + 255) / 256, 256, 0, stream>>>(node_feats, nf_bf, B * N * C / 4);
  cast_kernel<<<(C * C / 4 + 255) / 256, 256, 0, stream>>>(linear_w, lw_bf, C * C / 4);
  cast_kernel<<<(N * N / 4 + 255) / 256, 256, 0, stream>>>(q_w, qw_bf, N * N / 4);
  cast_kernel<<<(N * N / 4 + 255) / 256, 256, 0, stream>>>(k_w, kw_bf, N * N / 4);
  cast_kernel<<<(N * N / 4 + 255) / 256, 256, 0, stream>>>(v_w, vw_bf, N * N / 4);

  // degree normalization factors
  sigrow_kernel<<<B * N, 256, 0, stream>>>(adj, edge, dis);

  // G1: Xt[b,o,n] = leaky(lw @ nf^T + lb[o])  M=512,Nc=1024,K=512  BNT=128
  gemm256<128, 1, true, false, false, false, false><<<256, 512, 0, stream>>>(
      lw_bf, 0, nf_bf, (size_t)N * C, linear_b, nullptr, nullptr,
      Xt_bf, nullptr, C, N, C, C, 3, 1, 999);

  // LN1 over n (D=1024) -> Txln bf16
  ln_kernel<4, false><<<B * C, 256, 0, stream>>>(Xt_bf, n1w, n1b, Txln, N);

  // fused q|k: Txln @ [qw;kw]^T + [qb;kb]  M=512,Nc=2048,K=1024  BNT=256
  // x<4 -> q, x>=4 -> k (out2/bias2 pre-shifted by -1024 cols)
  gemm256<256, 2, false, false, false, true, false><<<256, 512, 0, stream>>>(
      Txln, (size_t)C * N, qw_bf, 0, q_b, k_b - 1024, nullptr,
      q_bf, (void*)(k_bf - 1024), C, N, N, N, 3, 1, 4);

  // v^T: vt[b,g,x] = leaky(v_w @ Txln^T + v_b[g])  M=1024,Nc=512,K=1024  BNT=128
  gemm256<128, 1, true, false, false, false, false><<<256, 512, 0, stream>>>(
      vw_bf, 0, Txln, (size_t)C * N, v_b, nullptr, nullptr,
      vt_bf, nullptr, N, C, N, N, 2, 2, 999);

  // att partials: q @ k^T  M=512,Nc=512, K=1024 split 2x512  BNT=128
  gemm256<128, 0, false, false, true, false, true><<<256, 512, 0, stream>>>(
      q_bf, (size_t)C * N, k_bf, (size_t)C * N, nullptr, nullptr, nullptr,
      att_raw, att_raw2, C, C, 512, N, 2, 1, 999);

  // softmax((p0+p1) * 1/32) -> att_bf
  softmax_kernel<<<B * C, 256, 0, stream>>>(att_raw, att_raw2, att_bf);

  // W_A normalized bf16 (overwrites bytes [0,32MiB): partials dead)
  wa_kernel<<<B * N * N / 4 / 256, 256, 0, stream>>>(adj, edge, dis, WA_bf);

  // Tx2[b,x,h] = Txln + att @ v   M=512,Nc=1024,K=512  BNT=128
  gemm256<128, 0, false, true, false, false, false><<<256, 512, 0, stream>>>(
      att_bf, (size_t)C * C, vt_bf, (size_t)N * C, nullptr, nullptr, Txln,
      Tx2_bf, nullptr, C, N, C, C, 3, 1, 999);

  // X3[b,n,o] = W_A @ X2   M=1024,Nc=512,K=1024  BNT=128
  gemm256<128, 0, false, false, false, false, false><<<256, 512, 0, stream>>>(
      WA_bf, (size_t)N * N, Tx2_bf, (size_t)C * N, nullptr, nullptr, nullptr,
      X3_bf, nullptr, N, C, N, N, 2, 2, 999);

  // final LN over o (D=512) -> f32 out
  ln_kernel<2, true><<<B * N, 256, 0, stream>>>(X3_bf, n2w, n2b, out, C);
}